// Round 6
// baseline (181.211 us; speedup 1.0000x reference)
//
#include <hip/hip_runtime.h>
#include <stdint.h>
#include <stddef.h>

typedef short bfrag __attribute__((ext_vector_type(8)));
typedef float f32x4 __attribute__((ext_vector_type(4)));
typedef float f32x4u __attribute__((ext_vector_type(4), aligned(4)));  // rows are only 4B-aligned

#define NSEQ 7
// feats packed in MFMA A-fragment order: [btile(1024)][step(18)][lane(64)][j(8)] bf16
// value = feat[btile*16 + (lane&15)][k], k = step*32 + (lane>>4)*8 + j

__constant__ int c_ks[5] = {1, 3, 5, 7, 9};

// per-ksize active MFMA K-steps (B is exactly zero outside): s in [lo, lo+n)
#define SLO0 3
#define SLO1 2
#define SLO2 1
#define SLO3 0
#define SLO4 0
#define SN0 1
#define SN1 3
#define SN2 5
#define SN3 6
#define SN4 7

// LDS layout (halfwords): staging [32][SHW] bf16 (SHW padded to ==24 mod 64);
// max SHW = 664 (L=18) -> 21248 hw staging; pmax int[32*80] (relu'd float bits) above.
// Total 52736 B -> 3 blocks/CU. Tiles 0/1 (samples 0-15 / 16-31) are disjoint LDS
// regions -> tile1 staging may overlap tile0 compute without hazards.
#define STAGE_MAX_HW 21248
#define XL_HW (STAGE_MAX_HW + 5120)

static __device__ __forceinline__ unsigned short f2bf(float f) {
  unsigned int u = __float_as_uint(f);
  u += 0x7FFFu + ((u >> 16) & 1u);   // RNE
  return (unsigned short)(u >> 16);
}

// ---------------- prep: pack conv weights + lin1 into B-fragment layout ----------
struct PrepArgs {
  const float* Wk[5];
  const float* lin1_w;
  bfrag* Wpack;
  bfrag* lin1pack;
};

__global__ __launch_bounds__(256) void prep_kernel(PrepArgs a) {
  int tid = blockIdx.x * 256 + threadIdx.x;
  const int NW = NSEQ * 5 * 7 * 64;
  if (tid < NW) {
    int lane = tid & 63, rest = tid >> 6;
    int step = rest % 7, nt = (rest / 7) % 5, seq = rest / 35;
    int quad = lane >> 4, f = lane & 15;
    int ks = c_ks[nt], off = (9 - ks) >> 1;
    const float* W = a.Wk[nt];
    bfrag s;
#pragma unroll
    for (int j = 0; j < 8; ++j) {
      int k = step * 32 + quad * 8 + j;
      int t = k / 24, c = k % 24;
      int tap = t - off;
      float val = 0.f;
      if (c < 20 && tap >= 0 && tap < ks)
        val = W[((seq * 16 + f) * 20 + c) * ks + tap] * 0.2f;  // fold /5
      s[j] = (short)f2bf(val);
    }
    a.Wpack[tid] = s;
  } else if (tid < NW + 4 * 18 * 64) {
    int t2 = tid - NW;
    int lane = t2 & 63, rest = t2 >> 6;
    int step = rest % 18, nt = rest / 18;
    int quad = lane >> 4, col = lane & 15;
    int n = nt * 16 + col;
    bfrag s;
#pragma unroll
    for (int j = 0; j < 8; ++j) {
      int k = step * 32 + quad * 8 + j;
      float val = (k < 560) ? a.lin1_w[n * 560 + k] : 0.f;  // zero rows k>=560 make feats pad inert
      s[j] = (short)f2bf(val);
    }
    a.lin1pack[t2] = s;
  }
}

// ---------------- conv+relu+gmax: sample-tile MFMA, register max over positions ----
struct ConvArgs {
  const float* x[NSEQ];
  const bfrag* Wpack;
  unsigned short* feats;   // packed A-frag layout, see top
};

template <int SLO, int SN>
static __device__ __forceinline__ void mfma_group(f32x4& acc, int s, const bfrag& Af,
                                                  const bfrag* BfBase) {
  if (s >= SLO && s < SLO + SN)
    acc = __builtin_amdgcn_mfma_f32_16x16x32_bf16(Af, BfBase[s - SLO], acc, 0, 0, 0);
}

// One 16-sample MFMA tile over all 5 filter groups. arow = A base (includes quad*8).
static __device__ __forceinline__ void tile_mfma(const unsigned short* arow, const bfrag* Bf,
                                                 f32x4 acc[5]) {
#pragma unroll
  for (int s = 0; s < 7; ++s) {
    bfrag Af = *(const bfrag*)(arow + s * 32);
    mfma_group<SLO0, SN0>(acc[0], s, Af, Bf + 0);
    mfma_group<SLO1, SN1>(acc[1], s, Af, Bf + 1);
    mfma_group<SLO2, SN2>(acc[2], s, Af, Bf + 4);
    mfma_group<SLO3, SN3>(acc[3], s, Af, Bf + 9);
    acc[4] = __builtin_amdgcn_mfma_f32_16x16x32_bf16(Af, Bf[15 + s], acc[4], 0, 0, 0);
  }
}

// Block = 32 samples (2 M-tiles of 16), software-pipelined:
//   stage t0 -> b1 -> {issue t1 loads; compute t0; cvt+write t1} -> b2 -> compute t1.
// Register max over positions; one 20-op atomicMax merge per wave per tile.
// Live set (phase 3): Bf 88 + acc 20 + vmax 20 + held 16 + addr ~12 ~= 156 < 168
// (3-waves/EU cap; (256,4)=128 caused scratch spills in r2).
template <int L>
__device__ __forceinline__ void conv_body(unsigned short* xl, const ConvArgs& a,
                                          const int seq, const int b0) {
  constexpr int Pv = L + 9;                 // 4 leading pad + L + 5 trailing pad
  constexpr int SHW0 = Pv * 24;
  constexpr int SHW = SHW0 + ((24 - (SHW0 & 63)) & 63);   // == 24 mod 64 halfwords
  constexpr int STAGE_HW = 32 * SHW;
  constexpr int NC = (L + 3) / 4;           // overlapping float4 chunks per row
  constexpr int NJ = 160 * NC;              // chunk-granular jobs per 16-sample tile
  constexpr int NJA = NJ > 512 ? 512 : NJ;  // async-held tile1 jobs (<=2 per thread)
  int* pmax = (int*)(xl + STAGE_MAX_HW);
  const int tid = threadIdx.x;
  const float* xg = a.x[seq];

  // phase 0: zero staging (covers halo + channel pad) and pmax
  for (int i = tid; i < STAGE_HW / 8; i += 256) ((uint4*)xl)[i] = uint4{0, 0, 0, 0};
  for (int i = tid; i < 640; i += 256) ((uint4*)pmax)[i] = uint4{0, 0, 0, 0};
  __syncthreads();

  // phase 1: stage tile0 (samples 0-15) -> bf16 [b][pos=xi+4][c]; job =
  // (sample, channel-pair, chunk); rows 2cp/2cp+1 contiguous in global.
  for (int j = tid; j < NJ; j += 256) {
    int s = j / (10 * NC), r2 = j - s * (10 * NC);
    int cp = r2 / NC, ci = r2 - cp * NC;
    int xi0 = (4 * ci > L - 4) ? (L - 4) : 4 * ci;   // overlapping tail chunk
    const float* rowA = xg + ((size_t)(b0 + s) * 20 + 2 * cp) * L + xi0;
    f32x4u fa = *(const f32x4u*)rowA;
    f32x4u fb = *(const f32x4u*)(rowA + L);
    unsigned short* dst = xl + s * SHW + (4 + xi0) * 24 + 2 * cp;
#pragma unroll
    for (int jj = 0; jj < 4; ++jj) {
      unsigned int pk;
      asm("v_cvt_pk_bf16_f32 %0, %1, %2" : "=v"(pk) : "v"(fa[jj]), "v"(fb[jj]));
      *(unsigned int*)(dst + jj * 24) = pk;   // 4B-aligned: SHW even, 2cp even
    }
  }

  const int wave = tid >> 6, lane = tid & 63, quad = lane >> 4, m = lane & 15;

  // Bf preload (global, independent of LDS) — issued before b1 so latency hides
  const bfrag* wp = a.Wpack + (size_t)(seq * 5 * 7) * 64 + lane;
  bfrag Bf[22];
  {
    int bi = 0;
#pragma unroll
    for (int i = 0; i < SN0; ++i) Bf[bi++] = wp[(0 * 7 + SLO0 + i) * 64];
#pragma unroll
    for (int i = 0; i < SN1; ++i) Bf[bi++] = wp[(1 * 7 + SLO1 + i) * 64];
#pragma unroll
    for (int i = 0; i < SN2; ++i) Bf[bi++] = wp[(2 * 7 + SLO2 + i) * 64];
#pragma unroll
    for (int i = 0; i < SN3; ++i) Bf[bi++] = wp[(3 * 7 + SLO3 + i) * 64];
#pragma unroll
    for (int i = 0; i < SN4; ++i) Bf[bi++] = wp[(4 * 7 + SLO4 + i) * 64];
  }
  // Bf base offsets per nt: {0, 1, 4, 9, 15}

  __syncthreads();   // b1: tile0 staged

  // phase 2: issue tile1 global loads early (held in regs; write happens after
  // tile0 compute). sched_barrier pins the loads above the MFMA section.
  f32x4u ra0, rb0, ra1, rb1;
  const bool v1 = (tid + 256) < NJA;
  {
    int j = tid;                            // always < NJ (NJ >= 320)
    int s = j / (10 * NC), r2 = j - s * (10 * NC);
    int cp = r2 / NC, ci = r2 - cp * NC;
    int xi0 = (4 * ci > L - 4) ? (L - 4) : 4 * ci;
    const float* rowA = xg + ((size_t)(b0 + 16 + s) * 20 + 2 * cp) * L + xi0;
    ra0 = *(const f32x4u*)rowA;
    rb0 = *(const f32x4u*)(rowA + L);
  }
  if (v1) {
    int j = tid + 256;
    int s = j / (10 * NC), r2 = j - s * (10 * NC);
    int cp = r2 / NC, ci = r2 - cp * NC;
    int xi0 = (4 * ci > L - 4) ? (L - 4) : 4 * ci;
    const float* rowA = xg + ((size_t)(b0 + 16 + s) * 20 + 2 * cp) * L + xi0;
    ra1 = *(const f32x4u*)rowA;
    rb1 = *(const f32x4u*)(rowA + L);
  }
  __builtin_amdgcn_sched_barrier(0);

  // phase 3/5: compute one 16-sample tile (positions round-robin over waves)
  auto compute_tile = [&](const int mt) {
    f32x4 vmax[5];
#pragma unroll
    for (int g = 0; g < 5; ++g) vmax[g] = f32x4{0.f, 0.f, 0.f, 0.f};  // relu folded
    for (int l = wave; l < L; l += 4) {
      const unsigned short* arow = &xl[(mt * 16 + m) * SHW + l * 24 + quad * 8];
      f32x4 acc[5];
#pragma unroll
      for (int g = 0; g < 5; ++g) acc[g] = f32x4{0.f, 0.f, 0.f, 0.f};
      tile_mfma(arow, Bf, acc);
#pragma unroll
      for (int g = 0; g < 5; ++g) {
#pragma unroll
        for (int r4 = 0; r4 < 4; ++r4) vmax[g][r4] = fmaxf(vmax[g][r4], acc[g][r4]);
      }
    }
    // merge the 4 waves' running maxima: C row = quad*4+r4 = sample, col m = filter
#pragma unroll
    for (int g = 0; g < 5; ++g) {
#pragma unroll
      for (int r4 = 0; r4 < 4; ++r4)
        atomicMax(&pmax[(mt * 16 + quad * 4 + r4) * 80 + g * 16 + m],
                  __float_as_int(vmax[g][r4]));
    }
  };

  compute_tile(0);

  // phase 4: write held tile1 data (vmcnt waits inserted by compiler), then any
  // leftover tile1 jobs (L>=16 only) synchronously.
  {
    int j = tid;
    int s = j / (10 * NC), r2 = j - s * (10 * NC);
    int cp = r2 / NC, ci = r2 - cp * NC;
    int xi0 = (4 * ci > L - 4) ? (L - 4) : 4 * ci;
    unsigned short* dst = xl + (16 + s) * SHW + (4 + xi0) * 24 + 2 * cp;
#pragma unroll
    for (int jj = 0; jj < 4; ++jj) {
      unsigned int pk;
      asm("v_cvt_pk_bf16_f32 %0, %1, %2" : "=v"(pk) : "v"(ra0[jj]), "v"(rb0[jj]));
      *(unsigned int*)(dst + jj * 24) = pk;
    }
  }
  if (v1) {
    int j = tid + 256;
    int s = j / (10 * NC), r2 = j - s * (10 * NC);
    int cp = r2 / NC, ci = r2 - cp * NC;
    int xi0 = (4 * ci > L - 4) ? (L - 4) : 4 * ci;
    unsigned short* dst = xl + (16 + s) * SHW + (4 + xi0) * 24 + 2 * cp;
#pragma unroll
    for (int jj = 0; jj < 4; ++jj) {
      unsigned int pk;
      asm("v_cvt_pk_bf16_f32 %0, %1, %2" : "=v"(pk) : "v"(ra1[jj]), "v"(rb1[jj]));
      *(unsigned int*)(dst + jj * 24) = pk;
    }
  }
  if (NJ > NJA) {
    for (int j = NJA + tid; j < NJ; j += 256) {
      int s = j / (10 * NC), r2 = j - s * (10 * NC);
      int cp = r2 / NC, ci = r2 - cp * NC;
      int xi0 = (4 * ci > L - 4) ? (L - 4) : 4 * ci;
      const float* rowA = xg + ((size_t)(b0 + 16 + s) * 20 + 2 * cp) * L + xi0;
      f32x4u fa = *(const f32x4u*)rowA;
      f32x4u fb = *(const f32x4u*)(rowA + L);
      unsigned short* dst = xl + (16 + s) * SHW + (4 + xi0) * 24 + 2 * cp;
#pragma unroll
      for (int jj = 0; jj < 4; ++jj) {
        unsigned int pk;
        asm("v_cvt_pk_bf16_f32 %0, %1, %2" : "=v"(pk) : "v"(fa[jj]), "v"(fb[jj]));
        *(unsigned int*)(dst + jj * 24) = pk;
      }
    }
  }

  __syncthreads();   // b2: tile1 staged

  compute_tile(1);

  __syncthreads();   // b3: pmax complete

  // store phase: 32 samples x 10 chunks of 8 consecutive k -> one 16B store each
  for (int r = tid; r < 320; r += 256) {
    int s = r / 10, c = r - (r / 10) * 10;
    int k0 = seq * 80 + c * 8;               // multiple of 8
    bfrag outv;
#pragma unroll
    for (int j = 0; j < 8; ++j)
      outv[j] = (short)f2bf(__int_as_float(pmax[s * 80 + c * 8 + j]));
    int step = k0 >> 5, q = (k0 >> 3) & 3;
    int b = b0 + s;
    *(bfrag*)(a.feats + ((size_t)(b >> 4) * 18 + step) * 512 + (size_t)(q * 16 + (b & 15)) * 8) = outv;
  }
}

__global__ __launch_bounds__(256, 3) void conv_kernel(ConvArgs a) {
  __shared__ __align__(16) unsigned short xl[XL_HW];   // 52736 B
  const int bid = blockIdx.x;
  const int seq = bid % 7;           // interleave seqs across the grid
  const int b0 = (bid / 7) * 32;
  switch (seq) {
    case 0: conv_body<12>(xl, a, 0, b0); break;
    case 1: conv_body< 7>(xl, a, 1, b0); break;
    case 2: conv_body< 8>(xl, a, 2, b0); break;
    case 3: conv_body<16>(xl, a, 3, b0); break;
    case 4: conv_body< 6>(xl, a, 4, b0); break;
    case 5: conv_body< 7>(xl, a, 5, b0); break;
    default: conv_body<18>(xl, a, 6, b0); break;
  }
}

// ---------------- MLP: feats(packed) -> sigmoid(@lin1^T+b1) -> @lin2^T+b2 ----------------
struct MlpArgs {
  const bfrag* feats;      // packed A-frag layout
  const bfrag* lin1pack;
  const float* lin1_b;
  const float* lin2_w;
  const float* lin2_b;
  float* out;
};

__global__ __launch_bounds__(256, 4) void mlp_kernel(MlpArgs a) {
  __shared__ float h[16 * 68];
  __shared__ float w2[64];
  const int tid = threadIdx.x;
  const int b0 = blockIdx.x * 16;
  if (tid < 64) w2[tid] = a.lin2_w[tid];
  const int wave = tid >> 6, lane = tid & 63, quad = lane >> 4, m = lane & 15;
  const int nt = wave;                     // one n-tile per wave
  bfrag Bf[18];
#pragma unroll
  for (int s = 0; s < 18; ++s) Bf[s] = a.lin1pack[(nt * 18 + s) * 64 + lane];
  const bfrag* ap = a.feats + (size_t)blockIdx.x * 18 * 64 + lane;  // coalesced 16B/lane
  f32x4 acc = {0.f, 0.f, 0.f, 0.f};
#pragma unroll
  for (int s = 0; s < 18; ++s)
    acc = __builtin_amdgcn_mfma_f32_16x16x32_bf16(ap[s * 64], Bf[s], acc, 0, 0, 0);
  int n = nt * 16 + m;
  float bias = a.lin1_b[n];
#pragma unroll
  for (int r = 0; r < 4; ++r) {
    float pre = acc[r] + bias;
    h[(quad * 4 + r) * 68 + n] = 1.f / (1.f + __expf(-pre));
  }
  __syncthreads();
  int bl = tid >> 4, q = tid & 15;         // 16 threads per sample, 4 h each
  const float* hr = &h[bl * 68 + q * 4];
  float s = hr[0] * w2[q * 4] + hr[1] * w2[q * 4 + 1] + hr[2] * w2[q * 4 + 2] + hr[3] * w2[q * 4 + 3];
  s += __shfl_xor(s, 1);
  s += __shfl_xor(s, 2);
  s += __shfl_xor(s, 4);
  s += __shfl_xor(s, 8);
  if (q == 0) a.out[b0 + bl] = s + a.lin2_b[0];
}

// ---------------- launch ----------------
extern "C" void kernel_launch(void* const* d_in, const int* in_sizes, int n_in,
                              void* d_out, int out_size, void* d_ws, size_t ws_size,
                              hipStream_t stream) {
  (void)in_sizes; (void)n_in; (void)out_size; (void)ws_size;
  char* ws = (char*)d_ws;
  bfrag* Wpack = (bfrag*)(ws + 0);                 // 15680*16 = 250,880 B
  bfrag* lin1pack = (bfrag*)(ws + 262144);         // 4608*16  =  73,728 B
  unsigned short* feats = (unsigned short*)(ws + 393216);  // 1024*18*64*16 = 18.87 MB

  PrepArgs pa;
  for (int j = 0; j < 5; ++j) pa.Wk[j] = (const float*)d_in[7 + j];
  pa.lin1_w = (const float*)d_in[12];
  pa.Wpack = Wpack;
  pa.lin1pack = lin1pack;
  prep_kernel<<<80, 256, 0, stream>>>(pa);

  ConvArgs ca;
  for (int i = 0; i < NSEQ; ++i) ca.x[i] = (const float*)d_in[i];
  ca.Wpack = Wpack;
  ca.feats = feats;
  // 3584 blocks: 512 per seq (32 samples each), seqs interleaved by bid%7
  conv_kernel<<<3584, 256, 0, stream>>>(ca);

  MlpArgs ma;
  ma.feats = (const bfrag*)feats;
  ma.lin1pack = lin1pack;
  ma.lin1_b = (const float*)d_in[13];
  ma.lin2_w = (const float*)d_in[14];
  ma.lin2_b = (const float*)d_in[15];
  ma.out = (float*)d_out;
  mlp_kernel<<<1024, 256, 0, stream>>>(ma);
}